// Round 2
// baseline (3329.420 us; speedup 1.0000x reference)
//
#include <hip/hip_runtime.h>
#include <stdint.h>

typedef unsigned short u16;
typedef __attribute__((ext_vector_type(8))) short s16x8;
typedef __attribute__((ext_vector_type(4))) float f32x4;

#define DEVFN static __device__ __forceinline__

constexpr int BB = 4, TT = 2048, DD = 2048, HH = 32;
constexpr int MM = BB * TT;                 // 8192 rows
constexpr size_t MD = (size_t)MM * DD;      // 16,777,216 elems

DEVFN u16 f2b(float f) {
  unsigned int b = __float_as_uint(f);
  unsigned int r = (b + 0x7fffu + ((b >> 16) & 1u)) >> 16;
  return (u16)r;
}
DEVFN float b2f(u16 u) { return __uint_as_float(((unsigned int)u) << 16); }
DEVFN ushort4 pack4(float4 v) {
  ushort4 o; o.x = f2b(v.x); o.y = f2b(v.y); o.z = f2b(v.z); o.w = f2b(v.w); return o;
}

// ---------- fused token-shift for the tm_w1 input: xxx = x + (sh-x)*x_maa ----------
__global__ __launch_bounds__(256) void k_xxx(
    const float* __restrict__ x, const float* __restrict__ prev,
    const float* __restrict__ xmaa, u16* __restrict__ xxxb,
    float* __restrict__ xlast) {
  size_t e = ((size_t)blockIdx.x * 256 + threadIdx.x) * 4;
  int d = (int)(e % DD);
  int m = (int)(e / DD);
  int b = m >> 11, t = m & (TT - 1);
  float4 xv = *(const float4*)(x + e);
  float4 sh = (t == 0) ? *(const float4*)(prev + (size_t)b * DD + d)
                       : *(const float4*)(x + e - DD);
  float4 xm = *(const float4*)(xmaa + d);
  float4 xx = make_float4(xv.x + (sh.x - xv.x) * xm.x, xv.y + (sh.y - xv.y) * xm.y,
                          xv.z + (sh.z - xv.z) * xm.z, xv.w + (sh.w - xv.w) * xm.w);
  *(ushort4*)(xxxb + e) = pack4(xx);
  if (t == TT - 1) *(float4*)(xlast + (size_t)b * DD + d) = xv;
}

// ---------------- generic f32 -> bf16 transposed (B^T) with zero pad ------
__global__ __launch_bounds__(256) void k_transpose(
    const float* __restrict__ src, u16* __restrict__ dst,
    int K, int N, int Kpad, int Npad) {
  __shared__ float tile[64][65];
  int k0 = blockIdx.x * 64, n0 = blockIdx.y * 64;
  int tid = threadIdx.x;
#pragma unroll
  for (int it = 0; it < 16; ++it) {
    int flat = it * 256 + tid;
    int r = flat >> 6, c = flat & 63;
    int kk = k0 + r, nn = n0 + c;
    tile[r][c] = (kk < K && nn < N) ? src[(size_t)kk * N + nn] : 0.f;
  }
  __syncthreads();
#pragma unroll
  for (int it = 0; it < 16; ++it) {
    int flat = it * 256 + tid;
    int r = flat >> 6, c = flat & 63;
    dst[(size_t)(n0 + r) * Kpad + (k0 + c)] = f2b(tile[c][r]);
  }
}

// tm_w1 (2048x160) -> [384][2048] bf16: row n = f*64+c maps to src col f*32+c (c<32), else 0
__global__ __launch_bounds__(256) void k_tmw1(const float* __restrict__ src,
                                              u16* __restrict__ dst) {
  int idx = blockIdx.x * 256 + threadIdx.x;  // 384*2048
  int n = idx >> 11, kk = idx & 2047;
  int f = n >> 6, c = n & 63;
  float v = (f < 5 && c < 32) ? src[(size_t)kk * 160 + f * 32 + c] : 0.f;
  dst[idx] = f2b(v);
}

// ---------------- bf16 MFMA GEMM, Out[M][N] = A[M][K] * Bt[N][K]^T --------
// 128x128 tile, BK=64, 4 waves of 4x4 16x16x32 frags. Epilogue modes:
// 0 bf16 id | 1 bf16 sigmoid | 2 bf16 silu | 3 bf16 tanh
// 4 f32  exp(-exp(v+colvec[col])) | 5 bf16 x+sx*(colvec[col]+v), sx from f32 x/prev
// 6 f32 id
__global__ __launch_bounds__(256) void gemm_bt(
    const u16* __restrict__ A, int lda, const u16* __restrict__ Bt, int ldb,
    void* __restrict__ Out, int ldc, int K, int mode,
    const float* __restrict__ colvec, const float* __restrict__ xf32,
    const float* __restrict__ prevf32) {
  __shared__ u16 As[128 * 72];
  __shared__ u16 Bs[128 * 72];
  const int tid = threadIdx.x;
  const int m0 = blockIdx.x * 128, n0 = blockIdx.y * 128;
  const int wv = tid >> 6, lane = tid & 63;
  const int wr = wv >> 1, wc = wv & 1;
  const int lrow = lane & 15, kgrp = lane >> 4;
  f32x4 acc[4][4];
#pragma unroll
  for (int i = 0; i < 4; i++)
#pragma unroll
    for (int j = 0; j < 4; j++) acc[i][j] = {0.f, 0.f, 0.f, 0.f};

  for (int k0 = 0; k0 < K; k0 += 64) {
#pragma unroll
    for (int it = 0; it < 4; ++it) {
      int flat = it * 2048 + tid * 8;
      int r = flat >> 6, c = flat & 63;
      uint4 va = *(const uint4*)(A + (size_t)(m0 + r) * lda + k0 + c);
      *(uint4*)(&As[r * 72 + c]) = va;
      uint4 vb = *(const uint4*)(Bt + (size_t)(n0 + r) * ldb + k0 + c);
      *(uint4*)(&Bs[r * 72 + c]) = vb;
    }
    __syncthreads();
#pragma unroll
    for (int ks = 0; ks < 64; ks += 32) {
      s16x8 af[4], bfr[4];
#pragma unroll
      for (int mi = 0; mi < 4; mi++)
        af[mi] = *(const s16x8*)(&As[(wr * 64 + mi * 16 + lrow) * 72 + ks + kgrp * 8]);
#pragma unroll
      for (int ni = 0; ni < 4; ni++)
        bfr[ni] = *(const s16x8*)(&Bs[(wc * 64 + ni * 16 + lrow) * 72 + ks + kgrp * 8]);
#pragma unroll
      for (int mi = 0; mi < 4; mi++)
#pragma unroll
        for (int ni = 0; ni < 4; ni++)
          acc[mi][ni] = __builtin_amdgcn_mfma_f32_16x16x32_bf16(af[mi], bfr[ni],
                                                                acc[mi][ni], 0, 0, 0);
    }
    __syncthreads();
  }
#pragma unroll
  for (int mi = 0; mi < 4; mi++) {
#pragma unroll
    for (int ni = 0; ni < 4; ni++) {
      int row0 = m0 + wr * 64 + mi * 16 + kgrp * 4;
      int col = n0 + wc * 64 + ni * 16 + lrow;
#pragma unroll
      for (int q = 0; q < 4; q++) {
        int row = row0 + q;
        size_t o = (size_t)row * ldc + col;
        float v = acc[mi][ni][q];
        if (mode == 0) {
          ((u16*)Out)[o] = f2b(v);
        } else if (mode == 1) {
          ((u16*)Out)[o] = f2b(1.f / (1.f + __expf(-v)));
        } else if (mode == 2) {
          ((u16*)Out)[o] = f2b(v / (1.f + __expf(-v)));
        } else if (mode == 3) {
          ((u16*)Out)[o] = f2b(tanhf(v));
        } else if (mode == 4) {
          ((float*)Out)[o] = __expf(-__expf(v + colvec[col]));
        } else if (mode == 5) {
          int b = row >> 11, t = row & (TT - 1);
          size_t xo = (size_t)row * DD + col;
          float xv = xf32[xo];
          float sh = (t == 0) ? prevf32[(size_t)b * DD + col] : xf32[xo - DD];
          ((u16*)Out)[o] = f2b(xv + (sh - xv) * (colvec[col] + v));
        } else {
          ((float*)Out)[o] = v;
        }
      }
    }
  }
}

// ---------------- WKV6 scan: block=(b,h), thread=v-col, state in regs -----
__global__ __launch_bounds__(64) void k_scan(
    const u16* __restrict__ r, const u16* __restrict__ k,
    const u16* __restrict__ v, const float* __restrict__ w,
    const float* __restrict__ u, const float* __restrict__ st_in,
    u16* __restrict__ wkv, float* __restrict__ st_out) {
  int bh = blockIdx.x;
  int b = bh >> 5, h = bh & 31;
  int j = threadIdx.x;
  float4 s[16];
  const float* si = st_in + (size_t)bh * 4096;
#pragma unroll
  for (int i = 0; i < 16; i++) {
    s[i].x = si[(i * 4 + 0) * 64 + j];
    s[i].y = si[(i * 4 + 1) * 64 + j];
    s[i].z = si[(i * 4 + 2) * 64 + j];
    s[i].w = si[(i * 4 + 3) * 64 + j];
  }
  float4 uu[16];
  const float* up = u + h * 64;
#pragma unroll
  for (int i = 0; i < 16; i++) uu[i] = *(const float4*)(up + i * 4);
  __shared__ __align__(16) float rs[64];
  __shared__ __align__(16) float ks[64];
  __shared__ __align__(16) float wsd[64];
  size_t base = (size_t)b * TT * DD + h * 64 + j;
  float rc = b2f(r[base]), kc = b2f(k[base]), vc = b2f(v[base]), wc = w[base];
  for (int t = 0; t < TT; ++t) {
    rs[j] = rc; ks[j] = kc; wsd[j] = wc;
    float vg = vc;
    __syncthreads();
    size_t nb = base + DD;
    if (t + 1 < TT) { rc = b2f(r[nb]); kc = b2f(k[nb]); vc = b2f(v[nb]); wc = w[nb]; }
    float acc = 0.f;
#pragma unroll
    for (int i = 0; i < 16; i++) {
      float4 r4 = *(const float4*)(rs + i * 4);
      float4 k4 = *(const float4*)(ks + i * 4);
      float4 w4 = *(const float4*)(wsd + i * 4);
      float4 u4 = uu[i];
      float4 s4 = s[i];
      float kv;
      kv = k4.x * vg; acc += r4.x * fmaf(u4.x, kv, s4.x); s4.x = fmaf(s4.x, w4.x, kv);
      kv = k4.y * vg; acc += r4.y * fmaf(u4.y, kv, s4.y); s4.y = fmaf(s4.y, w4.y, kv);
      kv = k4.z * vg; acc += r4.z * fmaf(u4.z, kv, s4.z); s4.z = fmaf(s4.z, w4.z, kv);
      kv = k4.w * vg; acc += r4.w * fmaf(u4.w, kv, s4.w); s4.w = fmaf(s4.w, w4.w, kv);
      s[i] = s4;
    }
    wkv[base] = f2b(acc);
    base = nb;
    __syncthreads();
  }
  float* so = st_out + (size_t)bh * 4096;
#pragma unroll
  for (int i = 0; i < 16; i++) {
    so[(i * 4 + 0) * 64 + j] = s[i].x;
    so[(i * 4 + 1) * 64 + j] = s[i].y;
    so[(i * 4 + 2) * 64 + j] = s[i].z;
    so[(i * 4 + 3) * 64 + j] = s[i].w;
  }
}

// ---------------- per-head groupnorm * ln * g -> bf16 ---------------------
__global__ __launch_bounds__(256) void k_gnorm(
    const u16* __restrict__ wkv, const u16* __restrict__ g,
    const float* __restrict__ lng, const float* __restrict__ lnb,
    u16* __restrict__ outg) {
  int gi = blockIdx.x * 4 + (threadIdx.x >> 6);
  int lane = threadIdx.x & 63;
  int row = gi >> 5, h = gi & 31;
  size_t o = (size_t)row * DD + h * 64 + lane;
  float val = b2f(wkv[o]);
  float s1 = val, s2 = val * val;
#pragma unroll
  for (int off = 32; off; off >>= 1) {
    s1 += __shfl_xor(s1, off);
    s2 += __shfl_xor(s2, off);
  }
  float mu = s1 * (1.f / 64.f);
  float var = s2 * (1.f / 64.f) - mu * mu;
  float nv = (val - mu) * rsqrtf(var + 1e-5f);
  int d = h * 64 + lane;
  float ov = (nv * lng[d] + lnb[d]) * b2f(g[o]);
  outg[o] = f2b(ov);
}

// --------------------------------------------------------------------------
extern "C" void kernel_launch(void* const* d_in, const int* in_sizes, int n_in,
                              void* d_out, int out_size, void* d_ws, size_t ws_size,
                              hipStream_t stream) {
  const float* x = (const float*)d_in[0];
  const float* prev = (const float*)d_in[1];
  const float* st = (const float*)d_in[2];
  const float* x_maa = (const float*)d_in[3];
  const float* w_maa = (const float*)d_in[4];
  const float* k_maa = (const float*)d_in[5];
  const float* v_maa = (const float*)d_in[6];
  const float* r_maa = (const float*)d_in[7];
  const float* g_maa = (const float*)d_in[8];
  const float* tm_w1 = (const float*)d_in[9];
  const float* tm_w2 = (const float*)d_in[10];
  const float* td_w1 = (const float*)d_in[11];
  const float* td_w2 = (const float*)d_in[12];
  const float* decay = (const float*)d_in[13];
  const float* first = (const float*)d_in[14];
  const float* W_r = (const float*)d_in[15];
  const float* W_k = (const float*)d_in[16];
  const float* W_v = (const float*)d_in[17];
  const float* W_g = (const float*)d_in[18];
  const float* W_o = (const float*)d_in[19];
  const float* ln_g = (const float*)d_in[20];
  const float* ln_b = (const float*)d_in[21];

  float* out = (float*)d_out;          // [M][D] f32; doubles as wf32 scratch pre-G6
  float* xlast = out + MD;
  float* stout = xlast + (size_t)BB * DD;
  float* wf32 = out;                   // w values, dead before G6 writes out

  // ---- workspace layout, ~212 MB total ----
  char* p = (char*)d_ws;
  const size_t SLOT = MD * 2;          // 32 MB bf16 [M][D]
  u16* slotA = (u16*)p; p += SLOT;     // xxx -> rbuf -> outg
  u16* slotB = (u16*)p; p += SLOT;     // branch input bxA -> wkv(bf16)
  u16* slotC = (u16*)p; p += SLOT;     // kbuf
  u16* slotD = (u16*)p; p += SLOT;     // vbuf
  u16* slotE = (u16*)p; p += SLOT;     // gbuf
  u16* mbuf = (u16*)p; p += (size_t)MM * 384 * 2;   // [M][384]
  u16* hbuf = (u16*)p; p += (size_t)MM * 128 * 2;   // [M][128]
  u16* Wrt = (u16*)p; p += (size_t)DD * DD * 2;
  u16* Wkt = (u16*)p; p += (size_t)DD * DD * 2;
  u16* Wvt = (u16*)p; p += (size_t)DD * DD * 2;
  u16* Wgt = (u16*)p; p += (size_t)DD * DD * 2;
  u16* Wot = (u16*)p; p += (size_t)DD * DD * 2;
  u16* tmw1t = (u16*)p; p += (size_t)384 * 2048 * 2;   // [384][2048]
  u16* w2t = (u16*)p; p += (size_t)5 * 2048 * 64 * 2;  // 5 x [2048][64]
  u16* tdw1t = (u16*)p; p += (size_t)128 * 2048 * 2;   // [128][2048]
  u16* tdw2t = (u16*)p; p += (size_t)2048 * 128 * 2;   // [2048][128]

  dim3 b256(256);
  // ---- weight prep ----
  k_transpose<<<dim3(32, 32), b256, 0, stream>>>(W_r, Wrt, 2048, 2048, 2048, 2048);
  k_transpose<<<dim3(32, 32), b256, 0, stream>>>(W_k, Wkt, 2048, 2048, 2048, 2048);
  k_transpose<<<dim3(32, 32), b256, 0, stream>>>(W_v, Wvt, 2048, 2048, 2048, 2048);
  k_transpose<<<dim3(32, 32), b256, 0, stream>>>(W_g, Wgt, 2048, 2048, 2048, 2048);
  k_transpose<<<dim3(32, 32), b256, 0, stream>>>(W_o, Wot, 2048, 2048, 2048, 2048);
  k_transpose<<<dim3(32, 2), b256, 0, stream>>>(td_w1, tdw1t, 2048, 64, 2048, 128);
  k_transpose<<<dim3(2, 32), b256, 0, stream>>>(td_w2, tdw2t, 64, 2048, 128, 2048);
  for (int f = 0; f < 5; ++f)
    k_transpose<<<dim3(1, 32), b256, 0, stream>>>(
        tm_w2 + (size_t)f * 32 * 2048, w2t + (size_t)f * 2048 * 64, 32, 2048, 64, 2048);
  k_tmw1<<<3072, b256, 0, stream>>>(tm_w1, tmw1t);

  // ---- token shift (tm_w1 input) + x_last ----
  k_xxx<<<(int)(MD / 4 / 256), b256, 0, stream>>>(x, prev, x_maa, slotA, xlast);

  // ---- G1: m = tanh(xxx @ tm_w1)  [M][384] ----
  gemm_bt<<<dim3(MM / 128, 3), b256, 0, stream>>>(slotA, 2048, tmw1t, 2048, mbuf, 384,
                                                  2048, 3, nullptr, nullptr, nullptr);

  // ---- per-branch: mix GEMM (mode 5) then projection GEMM ----
  const float* maas[5] = {w_maa, k_maa, v_maa, r_maa, g_maa};
  // r branch (f=3): -> slotA (xxx dead after G1)
  gemm_bt<<<dim3(MM / 128, 16), b256, 0, stream>>>(mbuf + 3 * 64, 384, w2t + (size_t)3 * 2048 * 64,
                                                   64, slotB, 2048, 64, 5, maas[3], x, prev);
  gemm_bt<<<dim3(MM / 128, 16), b256, 0, stream>>>(slotB, 2048, Wrt, 2048, slotA, 2048,
                                                   2048, 1, nullptr, nullptr, nullptr);
  // k branch (f=1): -> slotC
  gemm_bt<<<dim3(MM / 128, 16), b256, 0, stream>>>(mbuf + 1 * 64, 384, w2t + (size_t)1 * 2048 * 64,
                                                   64, slotB, 2048, 64, 5, maas[1], x, prev);
  gemm_bt<<<dim3(MM / 128, 16), b256, 0, stream>>>(slotB, 2048, Wkt, 2048, slotC, 2048,
                                                   2048, 0, nullptr, nullptr, nullptr);
  // v branch (f=2): -> slotD
  gemm_bt<<<dim3(MM / 128, 16), b256, 0, stream>>>(mbuf + 2 * 64, 384, w2t + (size_t)2 * 2048 * 64,
                                                   64, slotB, 2048, 64, 5, maas[2], x, prev);
  gemm_bt<<<dim3(MM / 128, 16), b256, 0, stream>>>(slotB, 2048, Wvt, 2048, slotD, 2048,
                                                   2048, 0, nullptr, nullptr, nullptr);
  // g branch (f=4): -> slotE
  gemm_bt<<<dim3(MM / 128, 16), b256, 0, stream>>>(mbuf + 4 * 64, 384, w2t + (size_t)4 * 2048 * 64,
                                                   64, slotB, 2048, 64, 5, maas[4], x, prev);
  gemm_bt<<<dim3(MM / 128, 16), b256, 0, stream>>>(slotB, 2048, Wgt, 2048, slotE, 2048,
                                                   2048, 2, nullptr, nullptr, nullptr);
  // w branch (f=0): -> hbuf -> wf32 (in d_out scratch region)
  gemm_bt<<<dim3(MM / 128, 16), b256, 0, stream>>>(mbuf + 0 * 64, 384, w2t + (size_t)0 * 2048 * 64,
                                                   64, slotB, 2048, 64, 5, maas[0], x, prev);
  gemm_bt<<<dim3(MM / 128, 1), b256, 0, stream>>>(slotB, 2048, tdw1t, 2048, hbuf, 128,
                                                  2048, 3, nullptr, nullptr, nullptr);
  gemm_bt<<<dim3(MM / 128, 16), b256, 0, stream>>>(hbuf, 128, tdw2t, 128, wf32, 2048,
                                                   128, 4, decay, nullptr, nullptr);

  // ---- WKV scan: r=slotA k=slotC v=slotD w=wf32 -> wkv(bf16)=slotB, new_state ----
  k_scan<<<BB * HH, 64, 0, stream>>>(slotA, slotC, slotD, wf32, first, st, slotB, stout);

  // ---- groupnorm * ln * g -> outg = slotA (rbuf dead) ----
  k_gnorm<<<MM * HH / 4, b256, 0, stream>>>(slotB, slotE, ln_g, ln_b, slotA);

  // ---- G6: out = outg @ W_o -> f32 d_out (overwrites wf32 scratch, now dead) ----
  gemm_bt<<<dim3(MM / 128, 16), b256, 0, stream>>>(slotA, 2048, Wot, 2048, out, 2048,
                                                   2048, 6, nullptr, nullptr, nullptr);
}

// Round 5
// 1719.930 us; speedup vs baseline: 1.9358x; 1.9358x over previous
//
#include <hip/hip_runtime.h>
#include <stdint.h>

typedef unsigned short u16;
typedef __attribute__((ext_vector_type(8))) short s16x8;
typedef __attribute__((ext_vector_type(4))) float f32x4;

#define DEVFN static __device__ __forceinline__

constexpr int BB = 4, TT = 2048, DD = 2048, HH = 32;
constexpr int MM = BB * TT;                 // 8192 rows
constexpr size_t MD = (size_t)MM * DD;      // 16,777,216 elems
constexpr int CC = 128, NC = 16;            // scan chunking: 16 chunks of 128 steps

DEVFN u16 f2b(float f) {
  unsigned int b = __float_as_uint(f);
  unsigned int r = (b + 0x7fffu + ((b >> 16) & 1u)) >> 16;
  return (u16)r;
}
DEVFN float b2f(u16 u) { return __uint_as_float(((unsigned int)u) << 16); }
DEVFN ushort4 pack4(float4 v) {
  ushort4 o; o.x = f2b(v.x); o.y = f2b(v.y); o.z = f2b(v.z); o.w = f2b(v.w); return o;
}

// async global->LDS, 16B per lane; LDS dest = wave-uniform base + lane*16
DEVFN void gload16(const void* g, void* l) {
  __builtin_amdgcn_global_load_lds(
      (const __attribute__((address_space(1))) unsigned int*)g,
      (__attribute__((address_space(3))) unsigned int*)l, 16, 0, 0);
}

// ---------- fused token-shift for the tm_w1 input: xxx = x + (sh-x)*x_maa ----------
__global__ __launch_bounds__(256) void k_xxx(
    const float* __restrict__ x, const float* __restrict__ prev,
    const float* __restrict__ xmaa, u16* __restrict__ xxxb,
    float* __restrict__ xlast) {
  size_t e = ((size_t)blockIdx.x * 256 + threadIdx.x) * 4;
  int d = (int)(e % DD);
  int m = (int)(e / DD);
  int b = m >> 11, t = m & (TT - 1);
  float4 xv = *(const float4*)(x + e);
  float4 sh = (t == 0) ? *(const float4*)(prev + (size_t)b * DD + d)
                       : *(const float4*)(x + e - DD);
  float4 xm = *(const float4*)(xmaa + d);
  float4 xx = make_float4(xv.x + (sh.x - xv.x) * xm.x, xv.y + (sh.y - xv.y) * xm.y,
                          xv.z + (sh.z - xv.z) * xm.z, xv.w + (sh.w - xv.w) * xm.w);
  *(ushort4*)(xxxb + e) = pack4(xx);
  if (t == TT - 1) *(float4*)(xlast + (size_t)b * DD + d) = xv;
}

// ---------------- generic f32 -> bf16 transposed (B^T) with zero pad ------
__global__ __launch_bounds__(256) void k_transpose(
    const float* __restrict__ src, u16* __restrict__ dst,
    int K, int N, int Kpad, int Npad) {
  __shared__ float tile[64][65];
  int k0 = blockIdx.x * 64, n0 = blockIdx.y * 64;
  int tid = threadIdx.x;
#pragma unroll
  for (int it = 0; it < 16; ++it) {
    int flat = it * 256 + tid;
    int r = flat >> 6, c = flat & 63;
    int kk = k0 + r, nn = n0 + c;
    tile[r][c] = (kk < K && nn < N) ? src[(size_t)kk * N + nn] : 0.f;
  }
  __syncthreads();
#pragma unroll
  for (int it = 0; it < 16; ++it) {
    int flat = it * 256 + tid;
    int r = flat >> 6, c = flat & 63;
    dst[(size_t)(n0 + r) * Kpad + (k0 + c)] = f2b(tile[c][r]);
  }
}

// tm_w1 (2048x160) -> [384][2048] bf16: row n = f*64+c maps to src col f*32+c (c<32), else 0
__global__ __launch_bounds__(256) void k_tmw1(const float* __restrict__ src,
                                              u16* __restrict__ dst) {
  int idx = blockIdx.x * 256 + threadIdx.x;  // 384*2048
  int n = idx >> 11, kk = idx & 2047;
  int f = n >> 6, c = n & 63;
  float v = (f < 5 && c < 32) ? src[(size_t)kk * 160 + f * 32 + c] : 0.f;
  dst[idx] = f2b(v);
}

// ---------------- bf16 MFMA GEMM, Out[M][N] = A[M][K] * Bt[N][K]^T --------
// 128x128 tile, BK=64, 4 waves of 4x4 16x16x32 frags.
// Staging via global_load_lds width-16 (m97 ladder): LDS linear [128][64],
// lane l -> global (row base+l/8, col (l&7)*8), lands at LDS byte 16*l.
// Epilogue modes:
// 0 bf16 id | 1 bf16 sigmoid | 2 bf16 silu | 3 bf16 tanh
// 4 f32  exp(-exp(v+colvec[col])) | 5 bf16 x+sx*(colvec[col]+v), sx from f32 x/prev
// 6 f32 id
__global__ __launch_bounds__(256) void gemm_bt(
    const u16* __restrict__ A, int lda, const u16* __restrict__ Bt, int ldb,
    void* __restrict__ Out, int ldc, int K, int mode,
    const float* __restrict__ colvec, const float* __restrict__ xf32,
    const float* __restrict__ prevf32) {
  __shared__ u16 As[128 * 64];
  __shared__ u16 Bs[128 * 64];
  const int tid = threadIdx.x;
  const int m0 = blockIdx.x * 128, n0 = blockIdx.y * 128;
  const int wv = tid >> 6, lane = tid & 63;
  const int wr = wv >> 1, wc = wv & 1;
  const int lrow = lane & 15, kgrp = lane >> 4;
  const int srow = lane >> 3;          // staging: row within 8-row group
  const int scol = (lane & 7) * 8;     // staging: col element (16 B chunk)
  f32x4 acc[4][4];
#pragma unroll
  for (int i = 0; i < 4; i++)
#pragma unroll
    for (int j = 0; j < 4; j++) acc[i][j] = {0.f, 0.f, 0.f, 0.f};

  for (int k0 = 0; k0 < K; k0 += 64) {
#pragma unroll
    for (int it = 0; it < 4; ++it) {
      int rbase = it * 32 + wv * 8;    // wave-uniform row group
      gload16(A + (size_t)(m0 + rbase + srow) * lda + k0 + scol, &As[rbase * 64]);
      gload16(Bt + (size_t)(n0 + rbase + srow) * ldb + k0 + scol, &Bs[rbase * 64]);
    }
    __syncthreads();   // compiler drains vmcnt(0) before s_barrier
#pragma unroll
    for (int ks = 0; ks < 64; ks += 32) {
      s16x8 af[4], bfr[4];
#pragma unroll
      for (int mi = 0; mi < 4; mi++)
        af[mi] = *(const s16x8*)(&As[(wr * 64 + mi * 16 + lrow) * 64 + ks + kgrp * 8]);
#pragma unroll
      for (int ni = 0; ni < 4; ni++)
        bfr[ni] = *(const s16x8*)(&Bs[(wc * 64 + ni * 16 + lrow) * 64 + ks + kgrp * 8]);
#pragma unroll
      for (int mi = 0; mi < 4; mi++)
#pragma unroll
        for (int ni = 0; ni < 4; ni++)
          acc[mi][ni] = __builtin_amdgcn_mfma_f32_16x16x32_bf16(af[mi], bfr[ni],
                                                                acc[mi][ni], 0, 0, 0);
    }
    __syncthreads();
  }
#pragma unroll
  for (int mi = 0; mi < 4; mi++) {
#pragma unroll
    for (int ni = 0; ni < 4; ni++) {
      int row0 = m0 + wr * 64 + mi * 16 + kgrp * 4;
      int col = n0 + wc * 64 + ni * 16 + lrow;
#pragma unroll
      for (int q = 0; q < 4; q++) {
        int row = row0 + q;
        size_t o = (size_t)row * ldc + col;
        float v = acc[mi][ni][q];
        if (mode == 0) {
          ((u16*)Out)[o] = f2b(v);
        } else if (mode == 1) {
          ((u16*)Out)[o] = f2b(1.f / (1.f + __expf(-v)));
        } else if (mode == 2) {
          ((u16*)Out)[o] = f2b(v / (1.f + __expf(-v)));
        } else if (mode == 3) {
          ((u16*)Out)[o] = f2b(tanhf(v));
        } else if (mode == 4) {
          ((float*)Out)[o] = __expf(-__expf(v + colvec[col]));
        } else if (mode == 5) {
          int b = row >> 11, t = row & (TT - 1);
          size_t xo = (size_t)row * DD + col;
          float xv = xf32[xo];
          float sh = (t == 0) ? prevf32[(size_t)b * DD + col] : xf32[xo - DD];
          ((u16*)Out)[o] = f2b(xv + (sh - xv) * (colvec[col] + v));
        } else {
          ((float*)Out)[o] = v;
        }
      }
    }
  }
}

// ============ chunked WKV6 scan ============
// s[k][v] <- s[k][v]*w_t[k] + k_t[k]*v_t[v]   (diagonal-linear in k)
// chunk composition: S_end = S_start * P_c + L_c,  P_c[k] = prod_t w_t[k]

// pass 1: per (bh, chunk) local scan from zero -> L (f32 [idx][k][v]), P (f32 [idx][k])
__global__ __launch_bounds__(64) void k_scan1(
    const u16* __restrict__ k, const u16* __restrict__ v,
    const float* __restrict__ w, float* __restrict__ L, float* __restrict__ P) {
  int idx = blockIdx.x;              // bh*NC + c
  int bh = idx / NC, c = idx % NC;
  int b = bh >> 5, h = bh & 31;
  int j = threadIdx.x;
  float4 s[16];
#pragma unroll
  for (int i = 0; i < 16; i++) s[i] = make_float4(0.f, 0.f, 0.f, 0.f);
  float pj = 1.f;
  __shared__ __align__(16) float ks[64];
  __shared__ __align__(16) float wsd[64];
  size_t base = ((size_t)b * TT + (size_t)c * CC) * DD + h * 64 + j;
  float kc = b2f(k[base]), vc = b2f(v[base]), wc = w[base];
  for (int t = 0; t < CC; ++t) {
    ks[j] = kc; wsd[j] = wc;
    float vg = vc, wcur = wc;
    __syncthreads();
    size_t nb = base + DD;
    if (t + 1 < CC) { kc = b2f(k[nb]); vc = b2f(v[nb]); wc = w[nb]; }
    pj *= wcur;
#pragma unroll
    for (int i = 0; i < 16; i++) {
      float4 k4 = *(const float4*)(ks + i * 4);
      float4 w4 = *(const float4*)(wsd + i * 4);
      float4 s4 = s[i];
      s4.x = fmaf(s4.x, w4.x, k4.x * vg);
      s4.y = fmaf(s4.y, w4.y, k4.y * vg);
      s4.z = fmaf(s4.z, w4.z, k4.z * vg);
      s4.w = fmaf(s4.w, w4.w, k4.w * vg);
      s[i] = s4;
    }
    base = nb;
    __syncthreads();
  }
  float* Lp = L + (size_t)idx * 4096;
#pragma unroll
  for (int i = 0; i < 16; i++) {
    Lp[(i * 4 + 0) * 64 + j] = s[i].x;
    Lp[(i * 4 + 1) * 64 + j] = s[i].y;
    Lp[(i * 4 + 2) * 64 + j] = s[i].z;
    Lp[(i * 4 + 3) * 64 + j] = s[i].w;
  }
  P[(size_t)idx * 64 + j] = pj;
}

// pass 2: per bh, sequential combine over chunks. Sstart[c] is stored into the
// slot of the already-consumed L[c-1] (same buffer LS) — chunk 0 reads st_in.
__global__ __launch_bounds__(64) void k_scan2(
    float* LS, const float* __restrict__ P, const float* __restrict__ st_in) {
  int bh = blockIdx.x;
  int j = threadIdx.x;
  const float* si = st_in + (size_t)bh * 4096;
  float4 s[16];
#pragma unroll
  for (int i = 0; i < 16; i++) {
    s[i].x = si[(i * 4 + 0) * 64 + j];
    s[i].y = si[(i * 4 + 1) * 64 + j];
    s[i].z = si[(i * 4 + 2) * 64 + j];
    s[i].w = si[(i * 4 + 3) * 64 + j];
  }
  for (int c = 0; c < NC; ++c) {
    size_t slot = ((size_t)bh * NC + c) * 4096;
    if (c > 0) {
      float* dst = LS + ((size_t)bh * NC + c - 1) * 4096;
#pragma unroll
      for (int i = 0; i < 16; i++) {
        dst[(i * 4 + 0) * 64 + j] = s[i].x;
        dst[(i * 4 + 1) * 64 + j] = s[i].y;
        dst[(i * 4 + 2) * 64 + j] = s[i].z;
        dst[(i * 4 + 3) * 64 + j] = s[i].w;
      }
    }
    const float* Pc = P + ((size_t)bh * NC + c) * 64;
#pragma unroll
    for (int i = 0; i < 16; i++) {
      float4 p4 = *(const float4*)(Pc + i * 4);  // uniform across lanes
      float lx = LS[slot + (i * 4 + 0) * 64 + j];
      float ly = LS[slot + (i * 4 + 1) * 64 + j];
      float lz = LS[slot + (i * 4 + 2) * 64 + j];
      float lw = LS[slot + (i * 4 + 3) * 64 + j];
      s[i].x = fmaf(s[i].x, p4.x, lx);
      s[i].y = fmaf(s[i].y, p4.y, ly);
      s[i].z = fmaf(s[i].z, p4.z, lz);
      s[i].w = fmaf(s[i].w, p4.w, lw);
    }
  }
}

// pass 3: per (bh, chunk) replay from true chunk-start state -> wkv, final state
__global__ __launch_bounds__(64) void k_scan3(
    const u16* __restrict__ r, const u16* __restrict__ k,
    const u16* __restrict__ v, const float* __restrict__ w,
    const float* __restrict__ u, const float* __restrict__ st_in,
    const float* __restrict__ LS, u16* __restrict__ wkv,
    float* __restrict__ st_out) {
  int idx = blockIdx.x;              // bh*NC + c
  int bh = idx / NC, c = idx % NC;
  int b = bh >> 5, h = bh & 31;
  int j = threadIdx.x;
  const float* sp = (c == 0) ? st_in + (size_t)bh * 4096
                             : LS + ((size_t)bh * NC + c - 1) * 4096;
  float4 s[16];
#pragma unroll
  for (int i = 0; i < 16; i++) {
    s[i].x = sp[(i * 4 + 0) * 64 + j];
    s[i].y = sp[(i * 4 + 1) * 64 + j];
    s[i].z = sp[(i * 4 + 2) * 64 + j];
    s[i].w = sp[(i * 4 + 3) * 64 + j];
  }
  float4 uu[16];
  const float* up = u + h * 64;
#pragma unroll
  for (int i = 0; i < 16; i++) uu[i] = *(const float4*)(up + i * 4);
  __shared__ __align__(16) float rs[64];
  __shared__ __align__(16) float ks[64];
  __shared__ __align__(16) float wsd[64];
  size_t base = ((size_t)b * TT + (size_t)c * CC) * DD + h * 64 + j;
  float rc = b2f(r[base]), kc = b2f(k[base]), vc = b2f(v[base]), wc = w[base];
  for (int t = 0; t < CC; ++t) {
    rs[j] = rc; ks[j] = kc; wsd[j] = wc;
    float vg = vc;
    __syncthreads();
    size_t nb = base + DD;
    if (t + 1 < CC) { rc = b2f(r[nb]); kc = b2f(k[nb]); vc = b2f(v[nb]); wc = w[nb]; }
    float acc = 0.f;
#pragma unroll
    for (int i = 0; i < 16; i++) {
      float4 r4 = *(const float4*)(rs + i * 4);
      float4 k4 = *(const float4*)(ks + i * 4);
      float4 w4 = *(const float4*)(wsd + i * 4);
      float4 u4 = uu[i];
      float4 s4 = s[i];
      float kv;
      kv = k4.x * vg; acc += r4.x * fmaf(u4.x, kv, s4.x); s4.x = fmaf(s4.x, w4.x, kv);
      kv = k4.y * vg; acc += r4.y * fmaf(u4.y, kv, s4.y); s4.y = fmaf(s4.y, w4.y, kv);
      kv = k4.z * vg; acc += r4.z * fmaf(u4.z, kv, s4.z); s4.z = fmaf(s4.z, w4.z, kv);
      kv = k4.w * vg; acc += r4.w * fmaf(u4.w, kv, s4.w); s4.w = fmaf(s4.w, w4.w, kv);
      s[i] = s4;
    }
    wkv[base] = f2b(acc);
    base = nb;
    __syncthreads();
  }
  if (c == NC - 1) {
    float* so = st_out + (size_t)bh * 4096;
#pragma unroll
    for (int i = 0; i < 16; i++) {
      so[(i * 4 + 0) * 64 + j] = s[i].x;
      so[(i * 4 + 1) * 64 + j] = s[i].y;
      so[(i * 4 + 2) * 64 + j] = s[i].z;
      so[(i * 4 + 3) * 64 + j] = s[i].w;
    }
  }
}

// ---------------- per-head groupnorm * ln * g -> bf16 ---------------------
__global__ __launch_bounds__(256) void k_gnorm(
    const u16* __restrict__ wkv, const u16* __restrict__ g,
    const float* __restrict__ lng, const float* __restrict__ lnb,
    u16* __restrict__ outg) {
  int gi = blockIdx.x * 4 + (threadIdx.x >> 6);
  int lane = threadIdx.x & 63;
  int row = gi >> 5, h = gi & 31;
  size_t o = (size_t)row * DD + h * 64 + lane;
  float val = b2f(wkv[o]);
  float s1 = val, s2 = val * val;
#pragma unroll
  for (int off = 32; off; off >>= 1) {
    s1 += __shfl_xor(s1, off);
    s2 += __shfl_xor(s2, off);
  }
  float mu = s1 * (1.f / 64.f);
  float var = s2 * (1.f / 64.f) - mu * mu;
  float nv = (val - mu) * rsqrtf(var + 1e-5f);
  int d = h * 64 + lane;
  float ov = (nv * lng[d] + lnb[d]) * b2f(g[o]);
  outg[o] = f2b(ov);
}

// --------------------------------------------------------------------------
extern "C" void kernel_launch(void* const* d_in, const int* in_sizes, int n_in,
                              void* d_out, int out_size, void* d_ws, size_t ws_size,
                              hipStream_t stream) {
  const float* x = (const float*)d_in[0];
  const float* prev = (const float*)d_in[1];
  const float* st = (const float*)d_in[2];
  const float* x_maa = (const float*)d_in[3];
  const float* w_maa = (const float*)d_in[4];
  const float* k_maa = (const float*)d_in[5];
  const float* v_maa = (const float*)d_in[6];
  const float* r_maa = (const float*)d_in[7];
  const float* g_maa = (const float*)d_in[8];
  const float* tm_w1 = (const float*)d_in[9];
  const float* tm_w2 = (const float*)d_in[10];
  const float* td_w1 = (const float*)d_in[11];
  const float* td_w2 = (const float*)d_in[12];
  const float* decay = (const float*)d_in[13];
  const float* first = (const float*)d_in[14];
  const float* W_r = (const float*)d_in[15];
  const float* W_k = (const float*)d_in[16];
  const float* W_v = (const float*)d_in[17];
  const float* W_g = (const float*)d_in[18];
  const float* W_o = (const float*)d_in[19];
  const float* ln_g = (const float*)d_in[20];
  const float* ln_b = (const float*)d_in[21];

  float* out = (float*)d_out;          // [M][D] f32; doubles as wf32 scratch pre-G6
  float* xlast = out + MD;
  float* stout = xlast + (size_t)BB * DD;
  float* wf32 = out;                   // w values, dead before G6 writes out

  // ---- workspace layout, ~212 MB total ----
  char* p = (char*)d_ws;
  const size_t SLOT = MD * 2;          // 32 MB bf16 [M][D]
  u16* slotA = (u16*)p; p += SLOT;     // xxx -> rbuf -> outg
  u16* slotB = (u16*)p; p += SLOT;     // branch input bxA -> wkv(bf16)
  u16* slotC = (u16*)p; p += SLOT;     // kbuf
  u16* slotD = (u16*)p; p += SLOT;     // vbuf
  u16* slotE = (u16*)p; p += SLOT;     // gbuf
  u16* mbuf = (u16*)p; p += (size_t)MM * 384 * 2;   // [M][384]
  u16* hbuf = (u16*)p; p += (size_t)MM * 128 * 2;   // [M][128]; P aliases after
  u16* Wrt = (u16*)p; p += (size_t)DD * DD * 2;
  u16* Wkt = (u16*)p; p += (size_t)DD * DD * 2;
  u16* Wvt = (u16*)p; p += (size_t)DD * DD * 2;
  u16* Wgt = (u16*)p; p += (size_t)DD * DD * 2;
  u16* Wot = (u16*)p; p += (size_t)DD * DD * 2;
  u16* tmw1t = (u16*)p; p += (size_t)384 * 2048 * 2;   // [384][2048]
  u16* w2t = (u16*)p; p += (size_t)5 * 2048 * 64 * 2;  // 5 x [2048][64]
  u16* tdw1t = (u16*)p; p += (size_t)128 * 2048 * 2;   // [128][2048]
  u16* tdw2t = (u16*)p; p += (size_t)2048 * 128 * 2;   // [2048][128]

  // scan scratch aliases dead buffers:
  //   LS (NC*128*4096 f32 = 32 MiB) over Wrt..Wgt (4 x 8 MiB, dead after projections)
  //   P  (2048*64 f32 = 512 KB) over hbuf (dead after G5)
  float* LS = (float*)Wrt;
  float* Pbuf = (float*)hbuf;

  dim3 b256(256);
  // ---- weight prep ----
  k_transpose<<<dim3(32, 32), b256, 0, stream>>>(W_r, Wrt, 2048, 2048, 2048, 2048);
  k_transpose<<<dim3(32, 32), b256, 0, stream>>>(W_k, Wkt, 2048, 2048, 2048, 2048);
  k_transpose<<<dim3(32, 32), b256, 0, stream>>>(W_v, Wvt, 2048, 2048, 2048, 2048);
  k_transpose<<<dim3(32, 32), b256, 0, stream>>>(W_g, Wgt, 2048, 2048, 2048, 2048);
  k_transpose<<<dim3(32, 32), b256, 0, stream>>>(W_o, Wot, 2048, 2048, 2048, 2048);
  k_transpose<<<dim3(32, 2), b256, 0, stream>>>(td_w1, tdw1t, 2048, 64, 2048, 128);
  k_transpose<<<dim3(2, 32), b256, 0, stream>>>(td_w2, tdw2t, 64, 2048, 128, 2048);
  for (int f = 0; f < 5; ++f)
    k_transpose<<<dim3(1, 32), b256, 0, stream>>>(
        tm_w2 + (size_t)f * 32 * 2048, w2t + (size_t)f * 2048 * 64, 32, 2048, 64, 2048);
  k_tmw1<<<3072, b256, 0, stream>>>(tm_w1, tmw1t);

  // ---- token shift (tm_w1 input) + x_last ----
  k_xxx<<<(int)(MD / 4 / 256), b256, 0, stream>>>(x, prev, x_maa, slotA, xlast);

  // ---- G1: m = tanh(xxx @ tm_w1)  [M][384] ----
  gemm_bt<<<dim3(MM / 128, 3), b256, 0, stream>>>(slotA, 2048, tmw1t, 2048, mbuf, 384,
                                                  2048, 3, nullptr, nullptr, nullptr);

  // ---- per-branch: mix GEMM (mode 5) then projection GEMM ----
  const float* maas[5] = {w_maa, k_maa, v_maa, r_maa, g_maa};
  // r branch (f=3)
  gemm_bt<<<dim3(MM / 128, 16), b256, 0, stream>>>(mbuf + 3 * 64, 384, w2t + (size_t)3 * 2048 * 64,
                                                   64, slotB, 2048, 64, 5, maas[3], x, prev);
  gemm_bt<<<dim3(MM / 128, 16), b256, 0, stream>>>(slotB, 2048, Wrt, 2048, slotA, 2048,
                                                   2048, 1, nullptr, nullptr, nullptr);
  // k branch (f=1)
  gemm_bt<<<dim3(MM / 128, 16), b256, 0, stream>>>(mbuf + 1 * 64, 384, w2t + (size_t)1 * 2048 * 64,
                                                   64, slotB, 2048, 64, 5, maas[1], x, prev);
  gemm_bt<<<dim3(MM / 128, 16), b256, 0, stream>>>(slotB, 2048, Wkt, 2048, slotC, 2048,
                                                   2048, 0, nullptr, nullptr, nullptr);
  // v branch (f=2)
  gemm_bt<<<dim3(MM / 128, 16), b256, 0, stream>>>(mbuf + 2 * 64, 384, w2t + (size_t)2 * 2048 * 64,
                                                   64, slotB, 2048, 64, 5, maas[2], x, prev);
  gemm_bt<<<dim3(MM / 128, 16), b256, 0, stream>>>(slotB, 2048, Wvt, 2048, slotD, 2048,
                                                   2048, 0, nullptr, nullptr, nullptr);
  // g branch (f=4)
  gemm_bt<<<dim3(MM / 128, 16), b256, 0, stream>>>(mbuf + 4 * 64, 384, w2t + (size_t)4 * 2048 * 64,
                                                   64, slotB, 2048, 64, 5, maas[4], x, prev);
  gemm_bt<<<dim3(MM / 128, 16), b256, 0, stream>>>(slotB, 2048, Wgt, 2048, slotE, 2048,
                                                   2048, 2, nullptr, nullptr, nullptr);
  // w branch (f=0): -> hbuf -> wf32 (in d_out scratch region)
  gemm_bt<<<dim3(MM / 128, 16), b256, 0, stream>>>(mbuf + 0 * 64, 384, w2t + (size_t)0 * 2048 * 64,
                                                   64, slotB, 2048, 64, 5, maas[0], x, prev);
  gemm_bt<<<dim3(MM / 128, 1), b256, 0, stream>>>(slotB, 2048, tdw1t, 2048, hbuf, 128,
                                                  2048, 3, nullptr, nullptr, nullptr);
  gemm_bt<<<dim3(MM / 128, 16), b256, 0, stream>>>(hbuf, 128, tdw2t, 128, wf32, 2048,
                                                   128, 4, decay, nullptr, nullptr);

  // ---- chunked WKV scan: r=slotA k=slotC v=slotD w=wf32 -> wkv=slotB, new_state ----
  k_scan1<<<BB * HH * NC, 64, 0, stream>>>(slotC, slotD, wf32, LS, Pbuf);
  k_scan2<<<BB * HH, 64, 0, stream>>>(LS, Pbuf, st);
  k_scan3<<<BB * HH * NC, 64, 0, stream>>>(slotA, slotC, slotD, wf32, first, st, LS,
                                           slotB, stout);

  // ---- groupnorm * ln * g -> outg = slotA (rbuf dead) ----
  k_gnorm<<<MM * HH / 4, b256, 0, stream>>>(slotB, slotE, ln_g, ln_b, slotA);

  // ---- G6: out = outg @ W_o -> f32 d_out (overwrites wf32 scratch, now dead) ----
  gemm_bt<<<dim3(MM / 128, 16), b256, 0, stream>>>(slotA, 2048, Wot, 2048, out, 2048,
                                                   2048, 6, nullptr, nullptr, nullptr);
}

// Round 6
// 1709.075 us; speedup vs baseline: 1.9481x; 1.0064x over previous
//
#include <hip/hip_runtime.h>
#include <stdint.h>

typedef unsigned short u16;
typedef __attribute__((ext_vector_type(8))) short s16x8;
typedef __attribute__((ext_vector_type(4))) float f32x4;

#define DEVFN static __device__ __forceinline__

constexpr int BB = 4, TT = 2048, DD = 2048, HH = 32;
constexpr int MM = BB * TT;                 // 8192 rows
constexpr size_t MD = (size_t)MM * DD;      // 16,777,216 elems
constexpr int CC = 128, NC = 16;            // scan chunking: 16 chunks of 128 steps

DEVFN u16 f2b(float f) {
  unsigned int b = __float_as_uint(f);
  unsigned int r = (b + 0x7fffu + ((b >> 16) & 1u)) >> 16;
  return (u16)r;
}
DEVFN float b2f(u16 u) { return __uint_as_float(((unsigned int)u) << 16); }
DEVFN ushort4 pack4(float4 v) {
  ushort4 o; o.x = f2b(v.x); o.y = f2b(v.y); o.z = f2b(v.z); o.w = f2b(v.w); return o;
}

// async global->LDS, 16B per lane; LDS dest = wave-uniform base + lane*16
DEVFN void gload16(const void* g, void* l) {
  __builtin_amdgcn_global_load_lds(
      (const __attribute__((address_space(1))) unsigned int*)g,
      (__attribute__((address_space(3))) unsigned int*)l, 16, 0, 0);
}

// ---------- fused token-shift for the tm_w1 input: xxx = x + (sh-x)*x_maa ----------
__global__ __launch_bounds__(256) void k_xxx(
    const float* __restrict__ x, const float* __restrict__ prev,
    const float* __restrict__ xmaa, u16* __restrict__ xxxb,
    float* __restrict__ xlast) {
  size_t e = ((size_t)blockIdx.x * 256 + threadIdx.x) * 4;
  int d = (int)(e % DD);
  int m = (int)(e / DD);
  int b = m >> 11, t = m & (TT - 1);
  float4 xv = *(const float4*)(x + e);
  float4 sh = (t == 0) ? *(const float4*)(prev + (size_t)b * DD + d)
                       : *(const float4*)(x + e - DD);
  float4 xm = *(const float4*)(xmaa + d);
  float4 xx = make_float4(xv.x + (sh.x - xv.x) * xm.x, xv.y + (sh.y - xv.y) * xm.y,
                          xv.z + (sh.z - xv.z) * xm.z, xv.w + (sh.w - xv.w) * xm.w);
  *(ushort4*)(xxxb + e) = pack4(xx);
  if (t == TT - 1) *(float4*)(xlast + (size_t)b * DD + d) = xv;
}

// ---------- per-branch token-shift mix: buf <- x + (sh-x)*(maa + buf) ----------
// in-place elementwise over the branch slot (buf holds mix bf16 on entry, bx on exit)
__global__ __launch_bounds__(256) void k_bx(
    const float* __restrict__ x, const float* __restrict__ prev,
    const float* __restrict__ maa, u16* __restrict__ buf) {
  size_t e = ((size_t)blockIdx.x * 256 + threadIdx.x) * 4;
  int d = (int)(e % DD);
  int m = (int)(e / DD);
  int b = m >> 11, t = m & (TT - 1);
  float4 xv = *(const float4*)(x + e);
  float4 sh = (t == 0) ? *(const float4*)(prev + (size_t)b * DD + d)
                       : *(const float4*)(x + e - DD);
  float4 ma = *(const float4*)(maa + d);
  ushort4 mu = *(const ushort4*)(buf + e);
  float4 o;
  o.x = xv.x + (sh.x - xv.x) * (ma.x + b2f(mu.x));
  o.y = xv.y + (sh.y - xv.y) * (ma.y + b2f(mu.y));
  o.z = xv.z + (sh.z - xv.z) * (ma.z + b2f(mu.z));
  o.w = xv.w + (sh.w - xv.w) * (ma.w + b2f(mu.w));
  *(ushort4*)(buf + e) = pack4(o);
}

// ---------------- generic f32 -> bf16 transposed (B^T) with zero pad ------
__global__ __launch_bounds__(256) void k_transpose(
    const float* __restrict__ src, u16* __restrict__ dst,
    int K, int N, int Kpad, int Npad) {
  __shared__ float tile[64][65];
  int k0 = blockIdx.x * 64, n0 = blockIdx.y * 64;
  int tid = threadIdx.x;
#pragma unroll
  for (int it = 0; it < 16; ++it) {
    int flat = it * 256 + tid;
    int r = flat >> 6, c = flat & 63;
    int kk = k0 + r, nn = n0 + c;
    tile[r][c] = (kk < K && nn < N) ? src[(size_t)kk * N + nn] : 0.f;
  }
  __syncthreads();
#pragma unroll
  for (int it = 0; it < 16; ++it) {
    int flat = it * 256 + tid;
    int r = flat >> 6, c = flat & 63;
    dst[(size_t)(n0 + r) * Kpad + (k0 + c)] = f2b(tile[c][r]);
  }
}

// tm_w1 (2048x160) -> [384][2048] bf16: row n = f*64+c maps to src col f*32+c (c<32), else 0
__global__ __launch_bounds__(256) void k_tmw1(const float* __restrict__ src,
                                              u16* __restrict__ dst) {
  int idx = blockIdx.x * 256 + threadIdx.x;  // 384*2048
  int n = idx >> 11, kk = idx & 2047;
  int f = n >> 6, c = n & 63;
  float v = (f < 5 && c < 32) ? src[(size_t)kk * 160 + f * 32 + c] : 0.f;
  dst[idx] = f2b(v);
}

// ---------------- bf16 MFMA GEMM, Out[M][N] = A[M][K] * Bt[N][K]^T --------
// 128x128 tile, BK=64, 4 waves of 4x4 16x16x32 frags, global_load_lds w16.
// Epilogue modes: 0 bf16 id | 1 bf16 sigmoid | 2 bf16 silu | 3 bf16 tanh
// 4 f32 exp(-exp(v+colvec[col])) | 6 f32 id
__global__ __launch_bounds__(256) void gemm_bt(
    const u16* __restrict__ A, int lda, const u16* __restrict__ Bt, int ldb,
    void* __restrict__ Out, int ldc, int K, int mode,
    const float* __restrict__ colvec) {
  __shared__ u16 As[128 * 64];
  __shared__ u16 Bs[128 * 64];
  const int tid = threadIdx.x;
  const int m0 = blockIdx.x * 128, n0 = blockIdx.y * 128;
  const int wv = tid >> 6, lane = tid & 63;
  const int wr = wv >> 1, wc = wv & 1;
  const int lrow = lane & 15, kgrp = lane >> 4;
  const int srow = lane >> 3;          // staging: row within 8-row group
  const int scol = (lane & 7) * 8;     // staging: col element (16 B chunk)
  f32x4 acc[4][4];
#pragma unroll
  for (int i = 0; i < 4; i++)
#pragma unroll
    for (int j = 0; j < 4; j++) acc[i][j] = {0.f, 0.f, 0.f, 0.f};

  for (int k0 = 0; k0 < K; k0 += 64) {
#pragma unroll
    for (int it = 0; it < 4; ++it) {
      int rbase = it * 32 + wv * 8;    // wave-uniform row group
      gload16(A + (size_t)(m0 + rbase + srow) * lda + k0 + scol, &As[rbase * 64]);
      gload16(Bt + (size_t)(n0 + rbase + srow) * ldb + k0 + scol, &Bs[rbase * 64]);
    }
    __syncthreads();   // compiler drains vmcnt(0) before s_barrier
#pragma unroll
    for (int ks = 0; ks < 64; ks += 32) {
      s16x8 af[4], bfr[4];
#pragma unroll
      for (int mi = 0; mi < 4; mi++)
        af[mi] = *(const s16x8*)(&As[(wr * 64 + mi * 16 + lrow) * 64 + ks + kgrp * 8]);
#pragma unroll
      for (int ni = 0; ni < 4; ni++)
        bfr[ni] = *(const s16x8*)(&Bs[(wc * 64 + ni * 16 + lrow) * 64 + ks + kgrp * 8]);
#pragma unroll
      for (int mi = 0; mi < 4; mi++)
#pragma unroll
        for (int ni = 0; ni < 4; ni++)
          acc[mi][ni] = __builtin_amdgcn_mfma_f32_16x16x32_bf16(af[mi], bfr[ni],
                                                                acc[mi][ni], 0, 0, 0);
    }
    __syncthreads();
  }
#pragma unroll
  for (int mi = 0; mi < 4; mi++) {
#pragma unroll
    for (int ni = 0; ni < 4; ni++) {
      int row0 = m0 + wr * 64 + mi * 16 + kgrp * 4;
      int col = n0 + wc * 64 + ni * 16 + lrow;
#pragma unroll
      for (int q = 0; q < 4; q++) {
        int row = row0 + q;
        size_t o = (size_t)row * ldc + col;
        float v = acc[mi][ni][q];
        if (mode == 0) {
          ((u16*)Out)[o] = f2b(v);
        } else if (mode == 1) {
          ((u16*)Out)[o] = f2b(1.f / (1.f + __expf(-v)));
        } else if (mode == 2) {
          ((u16*)Out)[o] = f2b(v / (1.f + __expf(-v)));
        } else if (mode == 3) {
          ((u16*)Out)[o] = f2b(tanhf(v));
        } else if (mode == 4) {
          ((float*)Out)[o] = __expf(-__expf(v + colvec[col]));
        } else {
          ((float*)Out)[o] = v;
        }
      }
    }
  }
}

// ============ chunked WKV6 scan ============
// s[k][v] <- s[k][v]*w_t[k] + k_t[k]*v_t[v]   (diagonal-linear in k)
// chunk composition: S_end = S_start * P_c + L_c,  P_c[k] = prod_t w_t[k]
// time loops unrolled x2: one barrier pair per 2 steps.

// pass 1: per (bh, chunk) local scan from zero -> L (f32 [idx][k][v]), P (f32 [idx][k])
__global__ __launch_bounds__(64) void k_scan1(
    const u16* __restrict__ k, const u16* __restrict__ v,
    const float* __restrict__ w, float* __restrict__ L, float* __restrict__ P) {
  int idx = blockIdx.x;              // bh*NC + c
  int bh = idx / NC, c = idx % NC;
  int b = bh >> 5, h = bh & 31;
  int j = threadIdx.x;
  float4 s[16];
#pragma unroll
  for (int i = 0; i < 16; i++) s[i] = make_float4(0.f, 0.f, 0.f, 0.f);
  float pj = 1.f;
  __shared__ __align__(16) float ks0[64], ws0[64], ks1[64], ws1[64];
  size_t base = ((size_t)b * TT + (size_t)c * CC) * DD + h * 64 + j;
  float kc0 = b2f(k[base]), vc0 = b2f(v[base]), wc0 = w[base];
  float kc1 = b2f(k[base + DD]), vc1 = b2f(v[base + DD]), wc1 = w[base + DD];
  for (int t = 0; t < CC; t += 2) {
    ks0[j] = kc0; ws0[j] = wc0; ks1[j] = kc1; ws1[j] = wc1;
    float vg0 = vc0, vg1 = vc1;
    pj *= wc0 * wc1;
    __syncthreads();
    if (t + 2 < CC) {
      size_t nb = base + 2 * DD;
      kc0 = b2f(k[nb]); vc0 = b2f(v[nb]); wc0 = w[nb];
      kc1 = b2f(k[nb + DD]); vc1 = b2f(v[nb + DD]); wc1 = w[nb + DD];
    }
#pragma unroll
    for (int i = 0; i < 16; i++) {
      float4 k40 = *(const float4*)(ks0 + i * 4);
      float4 w40 = *(const float4*)(ws0 + i * 4);
      float4 k41 = *(const float4*)(ks1 + i * 4);
      float4 w41 = *(const float4*)(ws1 + i * 4);
      float4 s4 = s[i];
      s4.x = fmaf(s4.x, w40.x, k40.x * vg0); s4.x = fmaf(s4.x, w41.x, k41.x * vg1);
      s4.y = fmaf(s4.y, w40.y, k40.y * vg0); s4.y = fmaf(s4.y, w41.y, k41.y * vg1);
      s4.z = fmaf(s4.z, w40.z, k40.z * vg0); s4.z = fmaf(s4.z, w41.z, k41.z * vg1);
      s4.w = fmaf(s4.w, w40.w, k40.w * vg0); s4.w = fmaf(s4.w, w41.w, k41.w * vg1);
      s[i] = s4;
    }
    base += 2 * DD;
    __syncthreads();
  }
  float* Lp = L + (size_t)idx * 4096;
#pragma unroll
  for (int i = 0; i < 16; i++) {
    Lp[(i * 4 + 0) * 64 + j] = s[i].x;
    Lp[(i * 4 + 1) * 64 + j] = s[i].y;
    Lp[(i * 4 + 2) * 64 + j] = s[i].z;
    Lp[(i * 4 + 3) * 64 + j] = s[i].w;
  }
  P[(size_t)idx * 64 + j] = pj;
}

// pass 2: per bh, sequential combine over chunks. Sstart[c] is stored into the
// slot of the already-consumed L[c-1] (same buffer LS) — chunk 0 reads st_in.
__global__ __launch_bounds__(64) void k_scan2(
    float* LS, const float* __restrict__ P, const float* __restrict__ st_in) {
  int bh = blockIdx.x;
  int j = threadIdx.x;
  const float* si = st_in + (size_t)bh * 4096;
  float4 s[16];
#pragma unroll
  for (int i = 0; i < 16; i++) {
    s[i].x = si[(i * 4 + 0) * 64 + j];
    s[i].y = si[(i * 4 + 1) * 64 + j];
    s[i].z = si[(i * 4 + 2) * 64 + j];
    s[i].w = si[(i * 4 + 3) * 64 + j];
  }
  for (int c = 0; c < NC; ++c) {
    size_t slot = ((size_t)bh * NC + c) * 4096;
    if (c > 0) {
      float* dst = LS + ((size_t)bh * NC + c - 1) * 4096;
#pragma unroll
      for (int i = 0; i < 16; i++) {
        dst[(i * 4 + 0) * 64 + j] = s[i].x;
        dst[(i * 4 + 1) * 64 + j] = s[i].y;
        dst[(i * 4 + 2) * 64 + j] = s[i].z;
        dst[(i * 4 + 3) * 64 + j] = s[i].w;
      }
    }
    const float* Pc = P + ((size_t)bh * NC + c) * 64;
#pragma unroll
    for (int i = 0; i < 16; i++) {
      float4 p4 = *(const float4*)(Pc + i * 4);  // uniform across lanes
      float lx = LS[slot + (i * 4 + 0) * 64 + j];
      float ly = LS[slot + (i * 4 + 1) * 64 + j];
      float lz = LS[slot + (i * 4 + 2) * 64 + j];
      float lw = LS[slot + (i * 4 + 3) * 64 + j];
      s[i].x = fmaf(s[i].x, p4.x, lx);
      s[i].y = fmaf(s[i].y, p4.y, ly);
      s[i].z = fmaf(s[i].z, p4.z, lz);
      s[i].w = fmaf(s[i].w, p4.w, lw);
    }
  }
}

// pass 3: per (bh, chunk) replay from true chunk-start state -> wkv, final state
__global__ __launch_bounds__(64) void k_scan3(
    const u16* __restrict__ r, const u16* __restrict__ k,
    const u16* __restrict__ v, const float* __restrict__ w,
    const float* __restrict__ u, const float* __restrict__ st_in,
    const float* __restrict__ LS, u16* __restrict__ wkv,
    float* __restrict__ st_out) {
  int idx = blockIdx.x;              // bh*NC + c
  int bh = idx / NC, c = idx % NC;
  int b = bh >> 5, h = bh & 31;
  int j = threadIdx.x;
  const float* sp = (c == 0) ? st_in + (size_t)bh * 4096
                             : LS + ((size_t)bh * NC + c - 1) * 4096;
  float4 s[16];
#pragma unroll
  for (int i = 0; i < 16; i++) {
    s[i].x = sp[(i * 4 + 0) * 64 + j];
    s[i].y = sp[(i * 4 + 1) * 64 + j];
    s[i].z = sp[(i * 4 + 2) * 64 + j];
    s[i].w = sp[(i * 4 + 3) * 64 + j];
  }
  float4 uu[16];
  const float* up = u + h * 64;
#pragma unroll
  for (int i = 0; i < 16; i++) uu[i] = *(const float4*)(up + i * 4);
  __shared__ __align__(16) float rs0[64], ks0[64], ws0[64];
  __shared__ __align__(16) float rs1[64], ks1[64], ws1[64];
  size_t base = ((size_t)b * TT + (size_t)c * CC) * DD + h * 64 + j;
  float rc0 = b2f(r[base]), kc0 = b2f(k[base]), vc0 = b2f(v[base]), wc0 = w[base];
  float rc1 = b2f(r[base + DD]), kc1 = b2f(k[base + DD]), vc1 = b2f(v[base + DD]),
        wc1 = w[base + DD];
  for (int t = 0; t < CC; t += 2) {
    rs0[j] = rc0; ks0[j] = kc0; ws0[j] = wc0;
    rs1[j] = rc1; ks1[j] = kc1; ws1[j] = wc1;
    float vg0 = vc0, vg1 = vc1;
    __syncthreads();
    if (t + 2 < CC) {
      size_t nb = base + 2 * DD;
      rc0 = b2f(r[nb]); kc0 = b2f(k[nb]); vc0 = b2f(v[nb]); wc0 = w[nb];
      rc1 = b2f(r[nb + DD]); kc1 = b2f(k[nb + DD]); vc1 = b2f(v[nb + DD]);
      wc1 = w[nb + DD];
    }
    float acc0 = 0.f, acc1 = 0.f;
#pragma unroll
    for (int i = 0; i < 16; i++) {
      float4 r40 = *(const float4*)(rs0 + i * 4);
      float4 k40 = *(const float4*)(ks0 + i * 4);
      float4 w40 = *(const float4*)(ws0 + i * 4);
      float4 r41 = *(const float4*)(rs1 + i * 4);
      float4 k41 = *(const float4*)(ks1 + i * 4);
      float4 w41 = *(const float4*)(ws1 + i * 4);
      float4 u4 = uu[i];
      float4 s4 = s[i];
      float kv;
      kv = k40.x * vg0; acc0 += r40.x * fmaf(u4.x, kv, s4.x); s4.x = fmaf(s4.x, w40.x, kv);
      kv = k41.x * vg1; acc1 += r41.x * fmaf(u4.x, kv, s4.x); s4.x = fmaf(s4.x, w41.x, kv);
      kv = k40.y * vg0; acc0 += r40.y * fmaf(u4.y, kv, s4.y); s4.y = fmaf(s4.y, w40.y, kv);
      kv = k41.y * vg1; acc1 += r41.y * fmaf(u4.y, kv, s4.y); s4.y = fmaf(s4.y, w41.y, kv);
      kv = k40.z * vg0; acc0 += r40.z * fmaf(u4.z, kv, s4.z); s4.z = fmaf(s4.z, w40.z, kv);
      kv = k41.z * vg1; acc1 += r41.z * fmaf(u4.z, kv, s4.z); s4.z = fmaf(s4.z, w41.z, kv);
      kv = k40.w * vg0; acc0 += r40.w * fmaf(u4.w, kv, s4.w); s4.w = fmaf(s4.w, w40.w, kv);
      kv = k41.w * vg1; acc1 += r41.w * fmaf(u4.w, kv, s4.w); s4.w = fmaf(s4.w, w41.w, kv);
      s[i] = s4;
    }
    wkv[base] = f2b(acc0);
    wkv[base + DD] = f2b(acc1);
    base += 2 * DD;
    __syncthreads();
  }
  if (c == NC - 1) {
    float* so = st_out + (size_t)bh * 4096;
#pragma unroll
    for (int i = 0; i < 16; i++) {
      so[(i * 4 + 0) * 64 + j] = s[i].x;
      so[(i * 4 + 1) * 64 + j] = s[i].y;
      so[(i * 4 + 2) * 64 + j] = s[i].z;
      so[(i * 4 + 3) * 64 + j] = s[i].w;
    }
  }
}

// ---------------- per-head groupnorm * ln * g -> bf16 ---------------------
__global__ __launch_bounds__(256) void k_gnorm(
    const u16* __restrict__ wkv, const u16* __restrict__ g,
    const float* __restrict__ lng, const float* __restrict__ lnb,
    u16* __restrict__ outg) {
  int gi = blockIdx.x * 4 + (threadIdx.x >> 6);
  int lane = threadIdx.x & 63;
  int row = gi >> 5, h = gi & 31;
  size_t o = (size_t)row * DD + h * 64 + lane;
  float val = b2f(wkv[o]);
  float s1 = val, s2 = val * val;
#pragma unroll
  for (int off = 32; off; off >>= 1) {
    s1 += __shfl_xor(s1, off);
    s2 += __shfl_xor(s2, off);
  }
  float mu = s1 * (1.f / 64.f);
  float var = s2 * (1.f / 64.f) - mu * mu;
  float nv = (val - mu) * rsqrtf(var + 1e-5f);
  int d = h * 64 + lane;
  float ov = (nv * lng[d] + lnb[d]) * b2f(g[o]);
  outg[o] = f2b(ov);
}

// --------------------------------------------------------------------------
extern "C" void kernel_launch(void* const* d_in, const int* in_sizes, int n_in,
                              void* d_out, int out_size, void* d_ws, size_t ws_size,
                              hipStream_t stream) {
  const float* x = (const float*)d_in[0];
  const float* prev = (const float*)d_in[1];
  const float* st = (const float*)d_in[2];
  const float* x_maa = (const float*)d_in[3];
  const float* w_maa = (const float*)d_in[4];
  const float* k_maa = (const float*)d_in[5];
  const float* v_maa = (const float*)d_in[6];
  const float* r_maa = (const float*)d_in[7];
  const float* g_maa = (const float*)d_in[8];
  const float* tm_w1 = (const float*)d_in[9];
  const float* tm_w2 = (const float*)d_in[10];
  const float* td_w1 = (const float*)d_in[11];
  const float* td_w2 = (const float*)d_in[12];
  const float* decay = (const float*)d_in[13];
  const float* first = (const float*)d_in[14];
  const float* W_r = (const float*)d_in[15];
  const float* W_k = (const float*)d_in[16];
  const float* W_v = (const float*)d_in[17];
  const float* W_g = (const float*)d_in[18];
  const float* W_o = (const float*)d_in[19];
  const float* ln_g = (const float*)d_in[20];
  const float* ln_b = (const float*)d_in[21];

  float* out = (float*)d_out;          // [M][D] f32; doubles as wf32 scratch pre-G6
  float* xlast = out + MD;
  float* stout = xlast + (size_t)BB * DD;
  float* wf32 = out;                   // w values, dead before G6 writes out

  // ---- workspace layout, ~212 MB total ----
  char* p = (char*)d_ws;
  const size_t SLOT = MD * 2;          // 32 MB bf16 [M][D]
  u16* slotA = (u16*)p; p += SLOT;     // xxx -> rbuf -> outg
  u16* slotB = (u16*)p; p += SLOT;     // mix/bx per branch -> wkv(bf16)
  u16* slotC = (u16*)p; p += SLOT;     // kbuf
  u16* slotD = (u16*)p; p += SLOT;     // vbuf
  u16* slotE = (u16*)p; p += SLOT;     // gbuf
  u16* mbuf = (u16*)p; p += (size_t)MM * 384 * 2;   // [M][384]
  u16* hbuf = (u16*)p; p += (size_t)MM * 128 * 2;   // [M][128]; P aliases after
  u16* Wrt = (u16*)p; p += (size_t)DD * DD * 2;
  u16* Wkt = (u16*)p; p += (size_t)DD * DD * 2;
  u16* Wvt = (u16*)p; p += (size_t)DD * DD * 2;
  u16* Wgt = (u16*)p; p += (size_t)DD * DD * 2;
  u16* Wot = (u16*)p; p += (size_t)DD * DD * 2;
  u16* tmw1t = (u16*)p; p += (size_t)384 * 2048 * 2;   // [384][2048]
  u16* w2t = (u16*)p; p += (size_t)5 * 2048 * 64 * 2;  // 5 x [2048][64]
  u16* tdw1t = (u16*)p; p += (size_t)128 * 2048 * 2;   // [128][2048]
  u16* tdw2t = (u16*)p; p += (size_t)2048 * 128 * 2;   // [2048][128]

  // scan scratch aliases dead buffers:
  //   LS (NC*128*4096 f32 = 32 MiB) over Wrt..Wgt (4 x 8 MiB, dead after projections)
  //   P  (2048*64 f32 = 512 KB) over hbuf (dead after G5)
  float* LS = (float*)Wrt;
  float* Pbuf = (float*)hbuf;

  dim3 b256(256);
  // ---- weight prep ----
  k_transpose<<<dim3(32, 32), b256, 0, stream>>>(W_r, Wrt, 2048, 2048, 2048, 2048);
  k_transpose<<<dim3(32, 32), b256, 0, stream>>>(W_k, Wkt, 2048, 2048, 2048, 2048);
  k_transpose<<<dim3(32, 32), b256, 0, stream>>>(W_v, Wvt, 2048, 2048, 2048, 2048);
  k_transpose<<<dim3(32, 32), b256, 0, stream>>>(W_g, Wgt, 2048, 2048, 2048, 2048);
  k_transpose<<<dim3(32, 32), b256, 0, stream>>>(W_o, Wot, 2048, 2048, 2048, 2048);
  k_transpose<<<dim3(32, 2), b256, 0, stream>>>(td_w1, tdw1t, 2048, 64, 2048, 128);
  k_transpose<<<dim3(2, 32), b256, 0, stream>>>(td_w2, tdw2t, 64, 2048, 128, 2048);
  for (int f = 0; f < 5; ++f)
    k_transpose<<<dim3(1, 32), b256, 0, stream>>>(
        tm_w2 + (size_t)f * 32 * 2048, w2t + (size_t)f * 2048 * 64, 32, 2048, 64, 2048);
  k_tmw1<<<3072, b256, 0, stream>>>(tm_w1, tmw1t);

  // ---- token shift (tm_w1 input) + x_last ----
  k_xxx<<<(int)(MD / 4 / 256), b256, 0, stream>>>(x, prev, x_maa, slotA, xlast);

  // ---- G1: m = tanh(xxx @ tm_w1)  [M][384] ----
  gemm_bt<<<dim3(MM / 128, 3), b256, 0, stream>>>(slotA, 2048, tmw1t, 2048, mbuf, 384,
                                                  2048, 3, nullptr);

  // ---- per-branch: mix GEMM (mode 0) -> k_bx (coalesced) -> projection ----
  const float* maas[5] = {w_maa, k_maa, v_maa, r_maa, g_maa};
  const int nbx = (int)(MD / 4 / 256);
  // r branch (f=3)
  gemm_bt<<<dim3(MM / 128, 16), b256, 0, stream>>>(mbuf + 3 * 64, 384,
                                                   w2t + (size_t)3 * 2048 * 64, 64,
                                                   slotB, 2048, 64, 0, nullptr);
  k_bx<<<nbx, b256, 0, stream>>>(x, prev, maas[3], slotB);
  gemm_bt<<<dim3(MM / 128, 16), b256, 0, stream>>>(slotB, 2048, Wrt, 2048, slotA, 2048,
                                                   2048, 1, nullptr);
  // k branch (f=1)
  gemm_bt<<<dim3(MM / 128, 16), b256, 0, stream>>>(mbuf + 1 * 64, 384,
                                                   w2t + (size_t)1 * 2048 * 64, 64,
                                                   slotB, 2048, 64, 0, nullptr);
  k_bx<<<nbx, b256, 0, stream>>>(x, prev, maas[1], slotB);
  gemm_bt<<<dim3(MM / 128, 16), b256, 0, stream>>>(slotB, 2048, Wkt, 2048, slotC, 2048,
                                                   2048, 0, nullptr);
  // v branch (f=2)
  gemm_bt<<<dim3(MM / 128, 16), b256, 0, stream>>>(mbuf + 2 * 64, 384,
                                                   w2t + (size_t)2 * 2048 * 64, 64,
                                                   slotB, 2048, 64, 0, nullptr);
  k_bx<<<nbx, b256, 0, stream>>>(x, prev, maas[2], slotB);
  gemm_bt<<<dim3(MM / 128, 16), b256, 0, stream>>>(slotB, 2048, Wvt, 2048, slotD, 2048,
                                                   2048, 0, nullptr);
  // g branch (f=4)
  gemm_bt<<<dim3(MM / 128, 16), b256, 0, stream>>>(mbuf + 4 * 64, 384,
                                                   w2t + (size_t)4 * 2048 * 64, 64,
                                                   slotB, 2048, 64, 0, nullptr);
  k_bx<<<nbx, b256, 0, stream>>>(x, prev, maas[4], slotB);
  gemm_bt<<<dim3(MM / 128, 16), b256, 0, stream>>>(slotB, 2048, Wgt, 2048, slotE, 2048,
                                                   2048, 2, nullptr);
  // w branch (f=0): -> hbuf -> wf32 (in d_out scratch region)
  gemm_bt<<<dim3(MM / 128, 16), b256, 0, stream>>>(mbuf + 0 * 64, 384,
                                                   w2t + (size_t)0 * 2048 * 64, 64,
                                                   slotB, 2048, 64, 0, nullptr);
  k_bx<<<nbx, b256, 0, stream>>>(x, prev, maas[0], slotB);
  gemm_bt<<<dim3(MM / 128, 1), b256, 0, stream>>>(slotB, 2048, tdw1t, 2048, hbuf, 128,
                                                  2048, 3, nullptr);
  gemm_bt<<<dim3(MM / 128, 16), b256, 0, stream>>>(hbuf, 128, tdw2t, 128, wf32, 2048,
                                                   128, 4, decay);

  // ---- chunked WKV scan: r=slotA k=slotC v=slotD w=wf32 -> wkv=slotB, new_state ----
  k_scan1<<<BB * HH * NC, 64, 0, stream>>>(slotC, slotD, wf32, LS, Pbuf);
  k_scan2<<<BB * HH, 64, 0, stream>>>(LS, Pbuf, st);
  k_scan3<<<BB * HH * NC, 64, 0, stream>>>(slotA, slotC, slotD, wf32, first, st, LS,
                                           slotB, stout);

  // ---- groupnorm * ln * g -> outg = slotA (rbuf dead) ----
  k_gnorm<<<MM * HH / 4, b256, 0, stream>>>(slotB, slotE, ln_g, ln_b, slotA);

  // ---- G6: out = outg @ W_o -> f32 d_out (overwrites wf32 scratch, now dead) ----
  gemm_bt<<<dim3(MM / 128, 16), b256, 0, stream>>>(slotA, 2048, Wot, 2048, out, 2048,
                                                   2048, 6, nullptr);
}